// Round 1
// 772.442 us; speedup vs baseline: 1.0816x; 1.0816x over previous
//
#include <hip/hip_runtime.h>

// 2-layer LSTM (PyTorch gate order i,f,g,o), L=2048, B=512, INPUT=78, H=4.
//
// Kernel 1 (memory-bound, unchanged since R4): LDS-staged input projection.
//   Output xg0[t][b][j][g] prescaled by +-log2e (g gate: +2log2e), bias1
//   (prescaled) at ws[0..15], laid out [j*4+g].
// Kernel 2 (latency/issue-bound recurrence, R6 restructure): 16 lanes per
//   (batch, layer) -- lane = b2*32 + layer*16 + j*4 + g. Each lane owns ONE
//   gate pre-activation, so the wave does 1 sigmoid-form activation + 1
//   tanh(c) per step (4 trans ops) instead of the old 8-lane layout's 10.
//   Gate gather within quad via quad_perm DPP; h broadcast across units and
//   the layer0->layer1 ship via 7 parallel ds_swizzle XORs (A_m = h[j^m],
//   B_m = y0[j^m]; weights permuted to match, layer0's wB = 0).
//   Cell state kept prescaled: cs = 2*log2e*c (fold via g-lane act consts).
//   Layer1 lanes stream their own bias dword (stride 0) as the dot base.
//   2 batches per wave -> 256 blocks = every CU. Prefetch depth 8, unroll 8.
//
// ws: [0,64) bias1_scaled | [20480 B, 20480+64MiB) xg0.

#define LSEQ  2048
#define BATCH 512
#define NIN   78
#define LOG2E 1.4426950408889634f

#define WS_BIAS_F  0
#define WS_XG_F    5120
#define XG_BYTES   ((unsigned)LSEQ * BATCH * 16u * 4u)

#define RPB  128
#define TPB1 128

__device__ __forceinline__ float rcp_(float x) { return __builtin_amdgcn_rcpf(x); }
__device__ __forceinline__ float ex2_(float x) { return __builtin_amdgcn_exp2f(x); }

template<int CTRL>
__device__ __forceinline__ float dppf(float x) {
  int r = __builtin_amdgcn_update_dpp(0, __builtin_bit_cast(int, x), CTRL, 0xf, 0xf, false);
  return __builtin_bit_cast(float, r);
}
template<int PAT>
__device__ __forceinline__ float swzf(float x) {
  int r = __builtin_amdgcn_ds_swizzle(__builtin_bit_cast(int, x), PAT);
  return __builtin_bit_cast(float, r);
}

// ---------------- kernel 1: input projection (LDS-staged) ----------------
__global__ __launch_bounds__(TPB1) void xg_kernel(
    const float* __restrict__ x, const float* __restrict__ Wih0,
    const float* __restrict__ bih0, const float* __restrict__ bhh0,
    const float* __restrict__ bih1, const float* __restrict__ bhh1,
    float* __restrict__ ws)
{
  __shared__ float xs[RPB * NIN];
  const int tid = threadIdx.x;
  const int r0  = blockIdx.x * RPB;

  if (blockIdx.x == 0 && tid < 16) {       // prescaled layer-1 bias [j*4+g]
    const int j = tid >> 2, g = tid & 3, row = j + 4 * g;
    const float s = (g == 2) ? 2.f * LOG2E : -LOG2E;
    ws[WS_BIAS_F + tid] = s * (bih1[row] + bhh1[row]);
  }

  const float4* gx = (const float4*)(x + (size_t)r0 * NIN);
  float4* ls = (float4*)xs;
  for (int i = tid; i < RPB * NIN / 4; i += TPB1) ls[i] = gx[i];
  __syncthreads();

  const float* xr = xs + tid * NIN;
  float acc[16];
#pragma unroll
  for (int row = 0; row < 16; ++row) acc[row] = bih0[row] + bhh0[row];
  for (int k = 0; k < NIN; ++k) {
    const float xk = xr[k];
#pragma unroll
    for (int row = 0; row < 16; ++row) acc[row] += xk * Wih0[row * NIN + k];
  }
#pragma unroll
  for (int row = 0; row < 16; ++row) {
    const float s = ((row >> 2) == 2) ? 2.f * LOG2E : -LOG2E;
    acc[row] *= s;
  }
  float* o = ws + WS_XG_F + (size_t)(r0 + tid) * 16;
#pragma unroll
  for (int j = 0; j < 4; ++j) {
    float4 v = make_float4(acc[j], acc[j + 4], acc[j + 8], acc[j + 12]);
    *(float4*)(o + j * 4) = v;
  }
}

// ---------------- kernel 2: recurrence (16 lanes per batch-layer) --------
__global__ __launch_bounds__(64) void lstm_rec(
    const float* __restrict__ wsr,
    const int* __restrict__ lens,
    const float* __restrict__ Whh0, const float* __restrict__ Whh1,
    const float* __restrict__ Wih1,
    float* __restrict__ out)
{
  const int lane  = threadIdx.x;
  const int g     = lane & 3;          // gate: 0=i 1=f 2=g 3=o
  const int j     = (lane >> 2) & 3;   // hidden unit
  const int layer = (lane >> 4) & 1;
  const int b     = blockIdx.x * 2 + (lane >> 5);

  const float sg = (g == 2) ? 2.f * LOG2E : -LOG2E;   // pre-activation scale
  // act = ka*rcp(1+exp2(P)) + kb : sigmoid lanes -> sigma; g lane -> 2log2e*tanh
  const float ka = (g == 2) ? -4.f * LOG2E : 1.f;
  const float kb = (g == 2) ?  2.f * LOG2E : 0.f;

  const int row4 = (g * 4 + j) * 4;    // PyTorch row = gate*4 + unit
  const float* whh = layer ? Whh1 : Whh0;
  float wA[4], wB[4];
#pragma unroll
  for (int m = 0; m < 4; ++m) {        // A_m = h[j^m] (ds_swizzle xor mapping)
    wA[m] = sg * whh[row4 + (j ^ m)];
    wB[m] = layer ? sg * Wih1[row4 + (j ^ m)] : 0.f;
  }
  const int len = lens[b];

  // layer0 lanes stream xg0[t][b][j*4+g]; layer1 lanes "stream" their own
  // prescaled bias dword (stride 0) so the dot base needs no per-iter select.
  unsigned ofs = layer ? (unsigned)((j * 4 + g) * 4)
                       : (unsigned)(WS_XG_F * 4 + (b * 16 + j * 4 + g) * 4);
  const unsigned stride = layer ? 0u : (unsigned)(BATCH * 16 * 4);
  const unsigned maxofs = (unsigned)(WS_XG_F * 4) + XG_BYTES - 4u;

  float* sp = out + b * 4 + j;         // stored by (layer==1, g==0) lanes

  float A0 = 0.f, A1 = 0.f, A2 = 0.f, A3 = 0.f;   // own-layer h broadcast
  float B0 = 0.f, B1 = 0.f, B2 = 0.f, B3 = 0.f;   // other-layer h (y0 feed)
  float cs = 0.f;                                  // cell state * 2log2e

  auto ld1 = [&](unsigned o) -> float {
    o = (o > maxofs) ? maxofs : o;
    return *(const float*)((const char*)wsr + o);
  };

  float buf[8];
#pragma unroll
  for (int p = 0; p < 8; ++p) { buf[p] = ld1(ofs); ofs += stride; }

  auto step = [&](const float base, int t, bool do_store) {
    // gate pre-activation: base + sum_m A_m*wA[m] + sum_m B_m*wB[m]
    float p0 = fmaf(A0, wA[0], base);
    p0 = fmaf(A1, wA[1], p0);
    float p1 = A2 * wA[2];
    p1 = fmaf(A3, wA[3], p1);
    float p2 = fmaf(B0, wB[0], B1 * wB[1]);
    float p3 = fmaf(B2, wB[2], B3 * wB[3]);
    const float P = (p0 + p1) + (p2 + p3);

    // one activation for the whole wave (1 exp2 + 1 rcp)
    const float r   = rcp_(1.f + ex2_(P));
    const float act = fmaf(ka, r, kb);

    // gather this unit's 4 gates within the quad
    const float vi = dppf<0x00>(act), vf = dppf<0x55>(act),
                vg = dppf<0xAA>(act), vo = dppf<0xFF>(act);

    // cs = sigma(f)*cs + sigma(i)*(2log2e*tanh(g));  tanh(c)=1-2/(1+2^cs)
    cs = fmaf(vf, cs, vi * vg);
    const float tc = fmaf(-2.f, rcp_(1.f + ex2_(cs)), 1.f);
    const float hq = vo * tc;          // h of own quad's unit, all 4 lanes

    // broadcast across units + ship across layers: 7 parallel xor swizzles
    A0 = hq;
    A1 = swzf<0x101F>(hq);             // lane ^ 4   -> h[j^1]
    A2 = swzf<0x201F>(hq);             // lane ^ 8   -> h[j^2]
    A3 = swzf<0x301F>(hq);             // lane ^ 12  -> h[j^3]
    B0 = swzf<0x401F>(hq);             // lane ^ 16  -> other layer h[j]
    B1 = swzf<0x501F>(hq);             // lane ^ 20
    B2 = swzf<0x601F>(hq);             // lane ^ 24
    B3 = swzf<0x701F>(hq);             // lane ^ 28

    if (do_store) {
      if (layer && g == 0) *sp = (t < len) ? hq : 0.f;
      sp += BATCH * 4;
    }
  };

  // iteration 0: layer0 computes t=0; layer1 output is garbage -> reset its
  // state but KEEP B (= shipped h0(t=0), the input for layer1's t=0).
  step(buf[0], -1, false);
  if (layer) { cs = 0.f; A0 = 0.f; A1 = 0.f; A2 = 0.f; A3 = 0.f; }
  buf[0] = ld1(ofs); ofs += stride;

  // iteration k: layer0 computes t=k, layer1 computes (and stores) t=k-1
#pragma unroll 8
  for (int k = 1; k <= LSEQ; ++k) {
    step(buf[k & 7], k - 1, true);
    buf[k & 7] = ld1(ofs); ofs += stride;
  }
}

extern "C" void kernel_launch(void* const* d_in, const int* in_sizes, int n_in,
                              void* d_out, int out_size, void* d_ws, size_t ws_size,
                              hipStream_t stream) {
  const float* x    = (const float*)d_in[0];
  const int*   lens = (const int*)d_in[1];
  const float* Wih0 = (const float*)d_in[2];
  const float* Whh0 = (const float*)d_in[3];
  const float* bih0 = (const float*)d_in[4];
  const float* bhh0 = (const float*)d_in[5];
  const float* Wih1 = (const float*)d_in[6];
  const float* Whh1 = (const float*)d_in[7];
  const float* bih1 = (const float*)d_in[8];
  const float* bhh1 = (const float*)d_in[9];
  float* ws  = (float*)d_ws;
  float* out = (float*)d_out;

  xg_kernel<<<(LSEQ * BATCH) / RPB, TPB1, 0, stream>>>(
      x, Wih0, bih0, bhh0, bih1, bhh1, ws);
  lstm_rec<<<BATCH / 2, 64, 0, stream>>>(
      ws, lens, Whh0, Whh1, Wih1, out);
}